// Round 13
// baseline (832.887 us; speedup 1.0000x reference)
//
#include <hip/hip_runtime.h>
#include <hip/hip_bf16.h>

typedef unsigned short ushortT;
typedef __attribute__((ext_vector_type(8))) short v8s;
typedef __attribute__((ext_vector_type(4))) float v4f;

// Problem sizes (fixed by reference)
#define B_N   8192
#define S_N   512
#define F_N   64
#define R_N   4096
#define D_N   256
#define T_N   16
#define SF_N  (S_N * F_N)

#define ROWS  16            // rows per block
#define NBLK  (B_N / ROWS)  // 512 blocks
#define NPASS 4             // DIAGNOSTIC: stream x 4x to make the stream kernel visible

__device__ __forceinline__ ushortT f2bf(float x) {
  __hip_bfloat16 b = __float2bfloat16(x);
  return *(ushortT*)&b;
}
__device__ __forceinline__ float bf2f(ushortT u) {
  __hip_bfloat16 b = *(__hip_bfloat16*)&u;
  return __bfloat162float(b);
}
__device__ __forceinline__ void splitHL8(const float* v, v8s& h8, v8s& l8) {
  union { short s[8]; v8s v; } H, L;
#pragma unroll
  for (int j = 0; j < 8; ++j) {
    const float x = v[j];
    const ushortT hb = f2bf(x);
    H.s[j] = (short)hb;
    L.s[j] = (short)f2bf(x - bf2f(hb));
  }
  h8 = H.v; l8 = L.v;
}

// ---- K0: reg -> frag-swizzled bf16 H/L + rsqh (verified R8-R12) --------------
__global__ __launch_bounds__(256) void k_prep(const float* __restrict__ reg,
                                              ushortT* __restrict__ regHs,
                                              ushortT* __restrict__ regLs,
                                              float* __restrict__ rsqh) {
  const int g = blockIdx.x;
  const int t = threadIdx.x;
  const int lane = t & 63;
  const int q = t >> 6;
  const int n16 = lane & 15;
  const int kg = lane >> 4;
  const int row = g * 16 + n16;
#pragma unroll
  for (int h = 0; h < 2; ++h) {
    const int k0 = q + h * 4;
    float v[8];
    *(float4*)&v[0] = *(const float4*)&reg[(size_t)row * D_N + k0 * 32 + kg * 8];
    *(float4*)&v[4] = *(const float4*)&reg[(size_t)row * D_N + k0 * 32 + kg * 8 + 4];
    v8s h8, l8;
    splitHL8(v, h8, l8);
    const size_t o = ((size_t)(g * 8 + k0) * 64 + lane) * 8;
    *(v8s*)&regHs[o] = h8;
    *(v8s*)&regLs[o] = l8;
  }
  const int r16 = t >> 4, seg = t & 15;
  const float* rp = &reg[(size_t)(g * 16 + r16) * D_N + seg * 16];
  float s = 0.f;
#pragma unroll
  for (int j = 0; j < 4; ++j) {
    const float4 v = *(const float4*)&rp[j * 4];
    s += v.x * v.x + v.y * v.y + v.z * v.z + v.w * v.w;
  }
#pragma unroll
  for (int m = 8; m >= 1; m >>= 1) s += __shfl_xor(s, m);
  if (seg == 0) rsqh[g * 16 + r16] = 0.5f * s;
}

// ---- K1 (DIAGNOSTIC x4 stream): mean of 16 rows -> xmG ----------------------
// Wave w streams rows 2w,2w+1; NPASS passes interleaved across the two rows so
// re-reads can't be served by L3 (machine reads ~2 GB between same-row passes).
// mean = acc / (S_N * NPASS) -- same value to fp noise; argmin margin ~1e4.
__global__ __launch_bounds__(512, 4) void k_mean4(const float* __restrict__ x,
                                                  float* __restrict__ xmG) {
  const int t = threadIdx.x;
  const int w = t >> 6;
  const int lane = t & 63;
  const int bm0 = blockIdx.x * ROWS;

  float a0[4] = {0.f, 0.f, 0.f, 0.f};
  float a1[4] = {0.f, 0.f, 0.f, 0.f};
#pragma unroll 1
  for (int pass = 0; pass < NPASS; ++pass) {
#pragma unroll
    for (int rr = 0; rr < 2; ++rr) {
      const v4f* xw = (const v4f*)(x + (size_t)(bm0 + 2 * w + rr) * SF_N);
      float* ac = rr ? a1 : a0;
      float c0 = 0.f, c1 = 0.f, c2 = 0.f, c3 = 0.f;
#pragma unroll 1
      for (int i0 = 0; i0 < 128; i0 += 16) {
        v4f vv[16];
#pragma unroll
        for (int u = 0; u < 16; ++u)
          vv[u] = __builtin_nontemporal_load(&xw[(size_t)(i0 + u) * 64 + lane]);
#pragma unroll
        for (int u = 0; u < 16; ++u) {
          c0 += vv[u][0]; c1 += vv[u][1]; c2 += vv[u][2]; c3 += vv[u][3];
        }
      }
      ac[0] += c0; ac[1] += c1; ac[2] += c2; ac[3] += c3;
    }
  }
#pragma unroll
  for (int rr = 0; rr < 2; ++rr) {
    float* ac = rr ? a1 : a0;
    float c0 = ac[0], c1 = ac[1], c2 = ac[2], c3 = ac[3];
    c0 += __shfl_xor(c0, 16); c1 += __shfl_xor(c1, 16);
    c2 += __shfl_xor(c2, 16); c3 += __shfl_xor(c3, 16);
    c0 += __shfl_xor(c0, 32); c1 += __shfl_xor(c1, 32);
    c2 += __shfl_xor(c2, 32); c3 += __shfl_xor(c3, 32);
    if (lane < 16) {
      const float inv = 1.0f / (float)(S_N * NPASS);
      float4 o; o.x = c0 * inv; o.y = c1 * inv; o.z = c2 * inv; o.w = c3 * inv;
      *(float4*)&xmG[(size_t)(bm0 + 2 * w + rr) * F_N + lane * 4] = o;
    }
  }
}

// ---- K2: proj -> frag LDS -> MFMA score -> emit + loss (R11 phase 1b/2/3) ----
__global__ __launch_bounds__(512, 4) void k_score(const float* __restrict__ xmG,
                                                  const float* __restrict__ W,
                                                  const float* __restrict__ bias,
                                                  const float* __restrict__ reg,
                                                  const ushortT* __restrict__ regHs,
                                                  const ushortT* __restrict__ regLs,
                                                  const float* __restrict__ rsqh,
                                                  float* __restrict__ out,
                                                  float* __restrict__ lossPart) {
  __shared__ __align__(16) float xm[ROWS][68];
  __shared__ __align__(16) ushortT xeHs[4096];
  __shared__ __align__(16) ushortT xeLs[4096];
  __shared__ float swv[8][ROWS];
  __shared__ int   swi[8][ROWS];
  __shared__ float srowloss[ROWS];
  __shared__ int   sbi[ROWS];

  const int t = threadIdx.x;
  const int w = t >> 6;
  const int lane = t & 63;
  const int bm0 = blockIdx.x * ROWS;

  if (t < 256) {
    const int row = t >> 4, f4 = (t & 15) * 4;
    *(float4*)&xm[row][f4] = *(const float4*)&xmG[(size_t)(bm0 + row) * F_N + f4];
  }
  __syncthreads();

  // proj -> H/L frag LDS
  {
    const int prow = t >> 5;
    const int dgr = t & 31;
    float pv[8];
#pragma unroll
    for (int dd = 0; dd < 8; ++dd) {
      const int d = dgr * 8 + dd;
      float p = bias[d];
#pragma unroll
      for (int k4 = 0; k4 < 16; ++k4) {
        const float4 wv = *(const float4*)&W[(size_t)d * F_N + k4 * 4];
        const float4 xv = *(const float4*)&xm[prow][k4 * 4];
        p = fmaf(wv.x, xv.x, p); p = fmaf(wv.y, xv.y, p);
        p = fmaf(wv.z, xv.z, p); p = fmaf(wv.w, xv.w, p);
      }
      pv[dd] = p;
    }
    const int d0 = dgr * 8;
    const int k0 = d0 >> 5, kgp = (d0 >> 3) & 3;
    v8s h8, l8;
    splitHL8(pv, h8, l8);
    const int idx = (k0 * 64 + kgp * 16 + prow) * 8;
    *(v8s*)&xeHs[idx] = h8;
    *(v8s*)&xeLs[idx] = l8;
  }
  __syncthreads();

  const int n16 = lane & 15;
  const int kg = lane >> 4;
  float bvj[4];
  int bij[4];
#pragma unroll
  for (int j = 0; j < 4; ++j) { bvj[j] = 3.4e38f; bij[j] = 0; }

  for (int c = 0; c < 8; ++c) {
    const int g0 = w * 32 + c * 4;
    v4f acc[4];
#pragma unroll
    for (int ni = 0; ni < 4; ++ni) acc[ni] = (v4f){0.f, 0.f, 0.f, 0.f};
    const ushortT* BH = regHs + (size_t)g0 * 4096 + lane * 8;
    const ushortT* BL = regLs + (size_t)g0 * 4096 + lane * 8;
#pragma unroll
    for (int k0 = 0; k0 < 8; ++k0) {
      const int ao = (k0 * 64 + lane) * 8;
      const v8s ah = *(const v8s*)&xeHs[ao];
      const v8s al = *(const v8s*)&xeLs[ao];
#pragma unroll
      for (int ni = 0; ni < 4; ++ni) {
        const v8s bh = *(const v8s*)&BH[(size_t)(ni * 8 + k0) * 512];
        const v8s bl = *(const v8s*)&BL[(size_t)(ni * 8 + k0) * 512];
        acc[ni] = __builtin_amdgcn_mfma_f32_16x16x32_bf16(ah, bh, acc[ni], 0, 0, 0);
        acc[ni] = __builtin_amdgcn_mfma_f32_16x16x32_bf16(ah, bl, acc[ni], 0, 0, 0);
        acc[ni] = __builtin_amdgcn_mfma_f32_16x16x32_bf16(al, bh, acc[ni], 0, 0, 0);
      }
    }
#pragma unroll
    for (int ni = 0; ni < 4; ++ni) {   // ascending col groups -> lowest idx on ties
      const float rq = rsqh[(g0 + ni) * 16 + n16];
      const int col = (g0 + ni) * 16 + n16;
#pragma unroll
      for (int j = 0; j < 4; ++j) {
        const float s = rq - acc[ni][j];
        if (s < bvj[j]) { bvj[j] = s; bij[j] = col; }
      }
    }
  }

#pragma unroll
  for (int j = 0; j < 4; ++j) {
    float v = bvj[j];
    int ix = bij[j];
#pragma unroll
    for (int m = 8; m >= 1; m >>= 1) {
      const float ov = __shfl_xor(v, m);
      const int oi = __shfl_xor(ix, m);
      if (ov < v || (ov == v && oi < ix)) { v = ov; ix = oi; }
    }
    if (n16 == 0) { swv[w][kg * 4 + j] = v; swi[w][kg * 4 + j] = ix; }
  }
  __syncthreads();

  if (t < ROWS) {
    float bv = swv[0][t];
    int bi = swi[0][t];
#pragma unroll
    for (int ww = 1; ww < 8; ++ww) {
      const float ov = swv[ww][t];
      const int oi = swi[ww][t];
      if (ov < bv || (ov == bv && oi < bi)) { bv = ov; bi = oi; }
    }
    sbi[t] = bi;
  }
  __syncthreads();

  {
    const int prow = t >> 5;
    const int seg = t & 31;
    const int d8 = seg * 8;
    const int gr = bm0 + prow;
    const int ix = sbi[prow];
    __align__(16) float sel[8];
    *(float4*)&sel[0] = *(const float4*)&reg[(size_t)ix * D_N + d8];
    *(float4*)&sel[4] = *(const float4*)&reg[(size_t)ix * D_N + d8 + 4];
#pragma unroll
    for (int tt = 0; tt < T_N; ++tt) {
      float* op = &out[((size_t)gr * T_N + tt) * D_N + d8];
      *(float4*)&op[0] = *(float4*)&sel[0];
      *(float4*)&op[4] = *(float4*)&sel[4];
    }
    const int k0 = d8 >> 5, kgp = (d8 >> 3) & 3;
    const int idx = (k0 * 64 + kgp * 16 + prow) * 8;
    const v8s vh = *(const v8s*)&xeHs[idx];
    const v8s vl = *(const v8s*)&xeLs[idx];
    float p = 0.f;
#pragma unroll
    for (int j = 0; j < 8; ++j) {
      const float xej = bf2f((ushortT)vh[j]) + bf2f((ushortT)vl[j]);
      const float dd = xej - sel[j];
      p = fmaf(dd, dd, p);
    }
#pragma unroll
    for (int m = 16; m >= 1; m >>= 1) p += __shfl_xor(p, m);
    if (seg == 0) srowloss[prow] = p;
  }
  __syncthreads();
  if (t == 0) {
    float lp = 0.f;
#pragma unroll
    for (int r = 0; r < ROWS; ++r) lp += srowloss[r];
    lossPart[blockIdx.x] = lp;
  }
}

// ---- K3: loss = sum(parts)/B ----
__global__ __launch_bounds__(512) void k_loss(const float* __restrict__ lossPart,
                                              float* __restrict__ out) {
  __shared__ float ws8[8];
  const int t = threadIdx.x;
  float s = lossPart[t];  // exactly 512 parts
#pragma unroll
  for (int m = 32; m >= 1; m >>= 1) s += __shfl_xor(s, m);
  if ((t & 63) == 0) ws8[t >> 6] = s;
  __syncthreads();
  if (t == 0) {
    float a = 0.f;
#pragma unroll
    for (int i = 0; i < 8; ++i) a += ws8[i];
    out[(size_t)B_N * T_N * D_N] = a / (float)B_N;
  }
}

extern "C" void kernel_launch(void* const* d_in, const int* in_sizes, int n_in,
                              void* d_out, int out_size, void* d_ws, size_t ws_size,
                              hipStream_t stream) {
  const float* x    = (const float*)d_in[0];
  const float* W    = (const float*)d_in[1];
  const float* bias = (const float*)d_in[2];
  const float* reg  = (const float*)d_in[3];
  float* out = (float*)d_out;

  // workspace: all regions fully rewritten every call (~6 MB)
  ushortT* regHs = (ushortT*)d_ws;                      // 2 MB, frag-swizzled
  ushortT* regLs = regHs + (size_t)R_N * D_N;           // 2 MB
  float*   rsqh  = (float*)(regLs + (size_t)R_N * D_N); // 4096
  float*   xmG   = rsqh + R_N;                          // 8192*64 = 2 MB
  float*   lossPart = xmG + (size_t)B_N * F_N;          // 512

  k_prep<<<dim3(R_N / 16), dim3(256), 0, stream>>>(reg, regHs, regLs, rsqh);
  k_mean4<<<dim3(NBLK), dim3(512), 0, stream>>>(x, xmG);
  k_score<<<dim3(NBLK), dim3(512), 0, stream>>>(xmG, W, bias, reg, regHs, regLs, rsqh,
                                                out, lossPart);
  k_loss<<<dim3(1), dim3(512), 0, stream>>>(lossPart, out);
}

// Round 14
// 355.556 us; speedup vs baseline: 2.3425x; 2.3425x over previous
//
#include <hip/hip_runtime.h>
#include <hip/hip_bf16.h>

typedef unsigned short ushortT;
typedef __attribute__((ext_vector_type(8))) short v8s;
typedef __attribute__((ext_vector_type(4))) float v4f;

// Problem sizes (fixed by reference)
#define B_N   8192
#define S_N   512
#define F_N   64
#define R_N   4096
#define D_N   256
#define T_N   16
#define SF_N  (S_N * F_N)

#define GR    16            // rows per group
#define NBLK  256           // 1 block/CU; 2 groups (32 rows) per block

__device__ __forceinline__ ushortT f2bf(float x) {
  __hip_bfloat16 b = __float2bfloat16(x);
  return *(ushortT*)&b;
}
__device__ __forceinline__ float bf2f(ushortT u) {
  __hip_bfloat16 b = *(__hip_bfloat16*)&u;
  return __bfloat162float(b);
}
__device__ __forceinline__ void splitHL8(const float* v, v8s& h8, v8s& l8) {
  union { short s[8]; v8s v; } H, L;
#pragma unroll
  for (int j = 0; j < 8; ++j) {
    const float x = v[j];
    const ushortT hb = f2bf(x);
    H.s[j] = (short)hb;
    L.s[j] = (short)f2bf(x - bf2f(hb));
  }
  h8 = H.v; l8 = L.v;
}

// ---- K0: reg -> frag-swizzled bf16 H/L + rsqh (verified R8-R13) --------------
__global__ __launch_bounds__(256) void k_prep(const float* __restrict__ reg,
                                              ushortT* __restrict__ regHs,
                                              ushortT* __restrict__ regLs,
                                              float* __restrict__ rsqh) {
  const int g = blockIdx.x;
  const int t = threadIdx.x;
  const int lane = t & 63;
  const int q = t >> 6;
  const int n16 = lane & 15;
  const int kg = lane >> 4;
  const int row = g * 16 + n16;
#pragma unroll
  for (int h = 0; h < 2; ++h) {
    const int k0 = q + h * 4;
    float v[8];
    *(float4*)&v[0] = *(const float4*)&reg[(size_t)row * D_N + k0 * 32 + kg * 8];
    *(float4*)&v[4] = *(const float4*)&reg[(size_t)row * D_N + k0 * 32 + kg * 8 + 4];
    v8s h8, l8;
    splitHL8(v, h8, l8);
    const size_t o = ((size_t)(g * 8 + k0) * 64 + lane) * 8;
    *(v8s*)&regHs[o] = h8;
    *(v8s*)&regLs[o] = l8;
  }
  const int r16 = t >> 4, seg = t & 15;
  const float* rp = &reg[(size_t)(g * 16 + r16) * D_N + seg * 16];
  float s = 0.f;
#pragma unroll
  for (int j = 0; j < 4; ++j) {
    const float4 v = *(const float4*)&rp[j * 4];
    s += v.x * v.x + v.y * v.y + v.z * v.z + v.w * v.w;
  }
#pragma unroll
  for (int m = 8; m >= 1; m >>= 1) s += __shfl_xor(s, m);
  if (seg == 0) rsqh[g * 16 + r16] = 0.5f * s;
}

// ---- Fused: interleaved {stream g1 || score g0} per-wave micro-phases --------
__global__ __launch_bounds__(512, 2) void k_fused(const float* __restrict__ x,
                                                  const float* __restrict__ W,
                                                  const float* __restrict__ bias,
                                                  const float* __restrict__ reg,
                                                  const ushortT* __restrict__ regHs,
                                                  const ushortT* __restrict__ regLs,
                                                  const float* __restrict__ rsqh,
                                                  float* __restrict__ out,
                                                  float* __restrict__ lossPart) {
  __shared__ __align__(16) float xm[GR][68];       // mean scratch (per group, reused)
  __shared__ __align__(16) ushortT xeHs[2][4096];  // xe H frags per group
  __shared__ __align__(16) ushortT xeLs[2][4096];
  __shared__ float swv[8][GR];
  __shared__ int   swi[8][GR];
  __shared__ float srowloss[2][GR];
  __shared__ int   sbi[GR];

  const int t = threadIdx.x;
  const int w = t >> 6;
  const int lane = t & 63;
  const int bm0 = blockIdx.x * (2 * GR);
  const int n16 = lane & 15;
  const int kg = lane >> 4;

  // write per-row mean (from 4 per-lane partials) after cross-subgroup shuffles
  auto finish_row = [&](float c0, float c1, float c2, float c3, int lr) {
    c0 += __shfl_xor(c0, 16); c1 += __shfl_xor(c1, 16);
    c2 += __shfl_xor(c2, 16); c3 += __shfl_xor(c3, 16);
    c0 += __shfl_xor(c0, 32); c1 += __shfl_xor(c1, 32);
    c2 += __shfl_xor(c2, 32); c3 += __shfl_xor(c3, 32);
    if (lane < 16) {
      const float inv = 1.0f / (float)S_N;
      float4 o; o.x = c0 * inv; o.y = c1 * inv; o.z = c2 * inv; o.w = c3 * inv;
      *(float4*)&xm[lr][lane * 4] = o;
    }
  };

  // projection of group slot g -> H/L frag LDS (all 512 threads)
  auto proj = [&](int g) {
    const int prow = t >> 5;
    const int dgr = t & 31;
    float pv[8];
#pragma unroll
    for (int dd = 0; dd < 8; ++dd) {
      const int d = dgr * 8 + dd;
      float p = bias[d];
#pragma unroll
      for (int k4 = 0; k4 < 16; ++k4) {
        const float4 wv = *(const float4*)&W[(size_t)d * F_N + k4 * 4];
        const float4 xv = *(const float4*)&xm[prow][k4 * 4];
        p = fmaf(wv.x, xv.x, p); p = fmaf(wv.y, xv.y, p);
        p = fmaf(wv.z, xv.z, p); p = fmaf(wv.w, xv.w, p);
      }
      pv[dd] = p;
    }
    const int d0 = dgr * 8;
    const int k0 = d0 >> 5, kgp = (d0 >> 3) & 3;
    v8s h8, l8;
    splitHL8(pv, h8, l8);
    const int idx = (k0 * 64 + kgp * 16 + prow) * 8;
    *(v8s*)&xeHs[g][idx] = h8;
    *(v8s*)&xeLs[g][idx] = l8;
  };

  // gather + emit + per-row loss for group slot g (uses sbi)
  auto emitg = [&](int g) {
    const int prow = t >> 5;
    const int seg = t & 31;
    const int d8 = seg * 8;
    const int gr = bm0 + g * GR + prow;
    const int ix = sbi[prow];
    __align__(16) float sel[8];
    *(float4*)&sel[0] = *(const float4*)&reg[(size_t)ix * D_N + d8];
    *(float4*)&sel[4] = *(const float4*)&reg[(size_t)ix * D_N + d8 + 4];
#pragma unroll
    for (int tt = 0; tt < T_N; ++tt) {
      float* op = &out[((size_t)gr * T_N + tt) * D_N + d8];
      *(float4*)&op[0] = *(float4*)&sel[0];
      *(float4*)&op[4] = *(float4*)&sel[4];
    }
    const int k0 = d8 >> 5, kgp = (d8 >> 3) & 3;
    const int idx = (k0 * 64 + kgp * 16 + prow) * 8;
    const v8s vh = *(const v8s*)&xeHs[g][idx];
    const v8s vl = *(const v8s*)&xeLs[g][idx];
    float p = 0.f;
#pragma unroll
    for (int j = 0; j < 8; ++j) {
      const float xej = bf2f((ushortT)vh[j]) + bf2f((ushortT)vl[j]);
      const float dd = xej - sel[j];
      p = fmaf(dd, dd, p);
    }
#pragma unroll
    for (int m = 16; m >= 1; m >>= 1) p += __shfl_xor(p, m);
    if (seg == 0) srowloss[g][prow] = p;
  };

  // block argmin over nstrips strips into sbi (ascending strip = ascending cols)
  auto block_argmin = [&](int nstrips) {
    if (t < GR) {
      float bv = swv[0][t];
      int bi = swi[0][t];
      for (int s = 1; s < nstrips; ++s) {
        const float ov = swv[s][t];
        const int oi = swi[s][t];
        if (ov < bv || (ov == bv && oi < bi)) { bv = ov; bi = oi; }
      }
      sbi[t] = bi;
    }
  };

  // ---------------- Prologue: stream group 0 (rows 2w,2w+1), 32-deep batches ----
  {
    const v4f* xr0 = (const v4f*)(x + (size_t)(bm0 + 2 * w + 0) * SF_N);
    const v4f* xr1 = (const v4f*)(x + (size_t)(bm0 + 2 * w + 1) * SF_N);
#pragma unroll
    for (int rr = 0; rr < 2; ++rr) {
      const v4f* xw = rr ? xr1 : xr0;
      float c0 = 0.f, c1 = 0.f, c2 = 0.f, c3 = 0.f;
#pragma unroll 1
      for (int i0 = 0; i0 < 128; i0 += 32) {
        v4f sb[32];
#pragma unroll
        for (int u = 0; u < 32; ++u)
          sb[u] = __builtin_nontemporal_load(&xw[(size_t)(i0 + u) * 64 + lane]);
#pragma unroll
        for (int u = 0; u < 32; ++u) {
          c0 += sb[u][0]; c1 += sb[u][1]; c2 += sb[u][2]; c3 += sb[u][3];
        }
      }
      finish_row(c0, c1, c2, c3, 2 * w + rr);
    }
  }
  __syncthreads();
  proj(0);
  __syncthreads();

  // ---------------- Main: score g0 (8 c-iters) interleaved with stream g1 ------
  float bvj[4];
  int bij[4];
#pragma unroll
  for (int j = 0; j < 4; ++j) { bvj[j] = 3.4e38f; bij[j] = 0; }
  float r0c[4] = {0.f, 0.f, 0.f, 0.f};
  float r1c[4] = {0.f, 0.f, 0.f, 0.f};
  {
    const v4f* xr0 = (const v4f*)(x + (size_t)(bm0 + GR + 2 * w + 0) * SF_N);
    const v4f* xr1 = (const v4f*)(x + (size_t)(bm0 + GR + 2 * w + 1) * SF_N);
#pragma unroll 1
    for (int c = 0; c < 8; ++c) {
      const int g0 = w * 32 + c * 4;
      const ushortT* BH = regHs + (size_t)g0 * 4096 + lane * 8;
      const ushortT* BL = regLs + (size_t)g0 * 4096 + lane * 8;
      v4f acc[4];
#pragma unroll
      for (int ni = 0; ni < 4; ++ni) acc[ni] = (v4f){0.f, 0.f, 0.f, 0.f};

      // micro-phase 1: stream 16 chunks of row0, consume (drains vmcnt)
      {
        v4f sb[16];
#pragma unroll
        for (int u = 0; u < 16; ++u)
          sb[u] = __builtin_nontemporal_load(&xr0[(size_t)(c * 16 + u) * 64 + lane]);
#pragma unroll
        for (int u = 0; u < 16; ++u) {
          r0c[0] += sb[u][0]; r0c[1] += sb[u][1];
          r0c[2] += sb[u][2]; r0c[3] += sb[u][3];
        }
      }
      // micro-phase 2: score half (k0 = 0..3) — VMEM queue empty, only L2 latency
#pragma unroll
      for (int k0 = 0; k0 < 4; ++k0) {
        const int ao = (k0 * 64 + lane) * 8;
        const v8s ah = *(const v8s*)&xeHs[0][ao];
        const v8s al = *(const v8s*)&xeLs[0][ao];
#pragma unroll
        for (int ni = 0; ni < 4; ++ni) {
          const v8s bh = *(const v8s*)&BH[(size_t)(ni * 8 + k0) * 512];
          const v8s bl = *(const v8s*)&BL[(size_t)(ni * 8 + k0) * 512];
          acc[ni] = __builtin_amdgcn_mfma_f32_16x16x32_bf16(ah, bh, acc[ni], 0, 0, 0);
          acc[ni] = __builtin_amdgcn_mfma_f32_16x16x32_bf16(ah, bl, acc[ni], 0, 0, 0);
          acc[ni] = __builtin_amdgcn_mfma_f32_16x16x32_bf16(al, bh, acc[ni], 0, 0, 0);
        }
      }
      // micro-phase 3: stream 16 chunks of row1, consume
      {
        v4f sb[16];
#pragma unroll
        for (int u = 0; u < 16; ++u)
          sb[u] = __builtin_nontemporal_load(&xr1[(size_t)(c * 16 + u) * 64 + lane]);
#pragma unroll
        for (int u = 0; u < 16; ++u) {
          r1c[0] += sb[u][0]; r1c[1] += sb[u][1];
          r1c[2] += sb[u][2]; r1c[3] += sb[u][3];
        }
      }
      // micro-phase 4: score half (k0 = 4..7)
#pragma unroll
      for (int k0 = 4; k0 < 8; ++k0) {
        const int ao = (k0 * 64 + lane) * 8;
        const v8s ah = *(const v8s*)&xeHs[0][ao];
        const v8s al = *(const v8s*)&xeLs[0][ao];
#pragma unroll
        for (int ni = 0; ni < 4; ++ni) {
          const v8s bh = *(const v8s*)&BH[(size_t)(ni * 8 + k0) * 512];
          const v8s bl = *(const v8s*)&BL[(size_t)(ni * 8 + k0) * 512];
          acc[ni] = __builtin_amdgcn_mfma_f32_16x16x32_bf16(ah, bh, acc[ni], 0, 0, 0);
          acc[ni] = __builtin_amdgcn_mfma_f32_16x16x32_bf16(ah, bl, acc[ni], 0, 0, 0);
          acc[ni] = __builtin_amdgcn_mfma_f32_16x16x32_bf16(al, bh, acc[ni], 0, 0, 0);
        }
      }
      // epilogue c: running per-row argmin (ascending cols -> lowest idx on ties)
#pragma unroll
      for (int ni = 0; ni < 4; ++ni) {
        const float rq = rsqh[(g0 + ni) * 16 + n16];
        const int col = (g0 + ni) * 16 + n16;
#pragma unroll
        for (int j = 0; j < 4; ++j) {
          const float s = rq - acc[ni][j];
          if (s < bvj[j]) { bvj[j] = s; bij[j] = col; }
        }
      }
    }
  }
  // lane-group reduce of g0 argmin -> strips, and finish g1 means
#pragma unroll
  for (int j = 0; j < 4; ++j) {
    float v = bvj[j];
    int ix = bij[j];
#pragma unroll
    for (int m = 8; m >= 1; m >>= 1) {
      const float ov = __shfl_xor(v, m);
      const int oi = __shfl_xor(ix, m);
      if (ov < v || (ov == v && oi < ix)) { v = ov; ix = oi; }
    }
    if (n16 == 0) { swv[w][kg * 4 + j] = v; swi[w][kg * 4 + j] = ix; }
  }
  finish_row(r0c[0], r0c[1], r0c[2], r0c[3], 2 * w + 0);
  finish_row(r1c[0], r1c[1], r1c[2], r1c[3], 2 * w + 1);
  __syncthreads();

  // argmin g0 + proj g1 (disjoint writes), then emit g0
  block_argmin(8);
  proj(1);
  __syncthreads();
  emitg(0);

  // ---------------- Tail: score g1 (pure, queue-clean) ----------------
#pragma unroll
  for (int j = 0; j < 4; ++j) { bvj[j] = 3.4e38f; bij[j] = 0; }
#pragma unroll 1
  for (int c = 0; c < 8; ++c) {
    const int g0 = w * 32 + c * 4;
    const ushortT* BH = regHs + (size_t)g0 * 4096 + lane * 8;
    const ushortT* BL = regLs + (size_t)g0 * 4096 + lane * 8;
    v4f acc[4];
#pragma unroll
    for (int ni = 0; ni < 4; ++ni) acc[ni] = (v4f){0.f, 0.f, 0.f, 0.f};
#pragma unroll
    for (int k0 = 0; k0 < 8; ++k0) {
      const int ao = (k0 * 64 + lane) * 8;
      const v8s ah = *(const v8s*)&xeHs[1][ao];
      const v8s al = *(const v8s*)&xeLs[1][ao];
#pragma unroll
      for (int ni = 0; ni < 4; ++ni) {
        const v8s bh = *(const v8s*)&BH[(size_t)(ni * 8 + k0) * 512];
        const v8s bl = *(const v8s*)&BL[(size_t)(ni * 8 + k0) * 512];
        acc[ni] = __builtin_amdgcn_mfma_f32_16x16x32_bf16(ah, bh, acc[ni], 0, 0, 0);
        acc[ni] = __builtin_amdgcn_mfma_f32_16x16x32_bf16(ah, bl, acc[ni], 0, 0, 0);
        acc[ni] = __builtin_amdgcn_mfma_f32_16x16x32_bf16(al, bh, acc[ni], 0, 0, 0);
      }
    }
#pragma unroll
    for (int ni = 0; ni < 4; ++ni) {
      const float rq = rsqh[(g0 + ni) * 16 + n16];
      const int col = (g0 + ni) * 16 + n16;
#pragma unroll
      for (int j = 0; j < 4; ++j) {
        const float s = rq - acc[ni][j];
        if (s < bvj[j]) { bvj[j] = s; bij[j] = col; }
      }
    }
  }
#pragma unroll
  for (int j = 0; j < 4; ++j) {
    float v = bvj[j];
    int ix = bij[j];
#pragma unroll
    for (int m = 8; m >= 1; m >>= 1) {
      const float ov = __shfl_xor(v, m);
      const int oi = __shfl_xor(ix, m);
      if (ov < v || (ov == v && oi < ix)) { v = ov; ix = oi; }
    }
    if (n16 == 0) { swv[w][kg * 4 + j] = v; swi[w][kg * 4 + j] = ix; }
  }
  __syncthreads();
  block_argmin(8);
  __syncthreads();
  emitg(1);
  __syncthreads();

  if (t == 0) {
    float lp = 0.f;
#pragma unroll
    for (int r = 0; r < GR; ++r) lp += srowloss[0][r] + srowloss[1][r];
    lossPart[blockIdx.x] = lp;
  }
}

// ---- K2: loss = sum(parts)/B ----
__global__ __launch_bounds__(256) void k_loss(const float* __restrict__ lossPart,
                                              float* __restrict__ out) {
  __shared__ float ws4[4];
  const int t = threadIdx.x;
  float s = lossPart[t];  // exactly 256 parts
#pragma unroll
  for (int m = 32; m >= 1; m >>= 1) s += __shfl_xor(s, m);
  if ((t & 63) == 0) ws4[t >> 6] = s;
  __syncthreads();
  if (t == 0)
    out[(size_t)B_N * T_N * D_N] = (ws4[0] + ws4[1] + ws4[2] + ws4[3]) / (float)B_N;
}

extern "C" void kernel_launch(void* const* d_in, const int* in_sizes, int n_in,
                              void* d_out, int out_size, void* d_ws, size_t ws_size,
                              hipStream_t stream) {
  const float* x    = (const float*)d_in[0];
  const float* W    = (const float*)d_in[1];
  const float* bias = (const float*)d_in[2];
  const float* reg  = (const float*)d_in[3];
  float* out = (float*)d_out;

  // workspace: all regions fully rewritten every call (~4 MB)
  ushortT* regHs = (ushortT*)d_ws;                      // 2 MB, frag-swizzled
  ushortT* regLs = regHs + (size_t)R_N * D_N;           // 2 MB
  float*   rsqh  = (float*)(regLs + (size_t)R_N * D_N); // 4096
  float*   lossPart = rsqh + R_N;                       // 256

  k_prep<<<dim3(R_N / 16), dim3(256), 0, stream>>>(reg, regHs, regLs, rsqh);
  k_fused<<<dim3(NBLK), dim3(512), 0, stream>>>(x, W, bias, reg, regHs, regLs, rsqh,
                                                out, lossPart);
  k_loss<<<dim3(1), dim3(256), 0, stream>>>(lossPart, out);
}

// Round 15
// 355.452 us; speedup vs baseline: 2.3432x; 1.0003x over previous
//
#include <hip/hip_runtime.h>
#include <hip/hip_bf16.h>

typedef unsigned short ushortT;
typedef __attribute__((ext_vector_type(8))) short v8s;
typedef __attribute__((ext_vector_type(4))) float v4f;

// Problem sizes (fixed by reference)
#define B_N   8192
#define S_N   512
#define F_N   64
#define R_N   4096
#define D_N   256
#define T_N   16
#define SF_N  (S_N * F_N)

#define GR    16            // rows per group
#define NBLK  256           // 1 block/CU; 2 groups (32 rows) per block

__device__ __forceinline__ ushortT f2bf(float x) {
  __hip_bfloat16 b = __float2bfloat16(x);
  return *(ushortT*)&b;
}
__device__ __forceinline__ float bf2f(ushortT u) {
  __hip_bfloat16 b = *(__hip_bfloat16*)&u;
  return __bfloat162float(b);
}
__device__ __forceinline__ void splitHL8(const float* v, v8s& h8, v8s& l8) {
  union { short s[8]; v8s v; } H, L;
#pragma unroll
  for (int j = 0; j < 8; ++j) {
    const float x = v[j];
    const ushortT hb = f2bf(x);
    H.s[j] = (short)hb;
    L.s[j] = (short)f2bf(x - bf2f(hb));
  }
  h8 = H.v; l8 = L.v;
}

// ---- K0: reg -> frag-swizzled bf16 H/L + rsqh (verified R8-R14) --------------
__global__ __launch_bounds__(256) void k_prep(const float* __restrict__ reg,
                                              ushortT* __restrict__ regHs,
                                              ushortT* __restrict__ regLs,
                                              float* __restrict__ rsqh) {
  const int g = blockIdx.x;
  const int t = threadIdx.x;
  const int lane = t & 63;
  const int q = t >> 6;
  const int n16 = lane & 15;
  const int kg = lane >> 4;
  const int row = g * 16 + n16;
#pragma unroll
  for (int h = 0; h < 2; ++h) {
    const int k0 = q + h * 4;
    float v[8];
    *(float4*)&v[0] = *(const float4*)&reg[(size_t)row * D_N + k0 * 32 + kg * 8];
    *(float4*)&v[4] = *(const float4*)&reg[(size_t)row * D_N + k0 * 32 + kg * 8 + 4];
    v8s h8, l8;
    splitHL8(v, h8, l8);
    const size_t o = ((size_t)(g * 8 + k0) * 64 + lane) * 8;
    *(v8s*)&regHs[o] = h8;
    *(v8s*)&regLs[o] = l8;
  }
  const int r16 = t >> 4, seg = t & 15;
  const float* rp = &reg[(size_t)(g * 16 + r16) * D_N + seg * 16];
  float s = 0.f;
#pragma unroll
  for (int j = 0; j < 4; ++j) {
    const float4 v = *(const float4*)&rp[j * 4];
    s += v.x * v.x + v.y * v.y + v.z * v.z + v.w * v.w;
  }
#pragma unroll
  for (int m = 8; m >= 1; m >>= 1) s += __shfl_xor(s, m);
  if (seg == 0) rsqh[g * 16 + r16] = 0.5f * s;
}

// ---- Fused: interleaved {stream g1 || score g0}, block-staggered B order -----
__global__ __launch_bounds__(512, 2) void k_fused(const float* __restrict__ x,
                                                  const float* __restrict__ W,
                                                  const float* __restrict__ bias,
                                                  const float* __restrict__ reg,
                                                  const ushortT* __restrict__ regHs,
                                                  const ushortT* __restrict__ regLs,
                                                  const float* __restrict__ rsqh,
                                                  float* __restrict__ out,
                                                  float* __restrict__ lossPart) {
  __shared__ __align__(16) float xm[GR][68];       // mean scratch (per group, reused)
  __shared__ __align__(16) ushortT xeHs[2][4096];  // xe H frags per group
  __shared__ __align__(16) ushortT xeLs[2][4096];
  __shared__ float swv[8][GR];
  __shared__ int   swi[8][GR];
  __shared__ float srowloss[2][GR];
  __shared__ int   sbi[GR];

  const int t = threadIdx.x;
  const int w = t >> 6;
  const int lane = t & 63;
  const int bm0 = blockIdx.x * (2 * GR);
  const int n16 = lane & 15;
  const int kg = lane >> 4;
  const int cstag = (int)blockIdx.x & 7;   // per-block B-window stagger

  auto finish_row = [&](float c0, float c1, float c2, float c3, int lr) {
    c0 += __shfl_xor(c0, 16); c1 += __shfl_xor(c1, 16);
    c2 += __shfl_xor(c2, 16); c3 += __shfl_xor(c3, 16);
    c0 += __shfl_xor(c0, 32); c1 += __shfl_xor(c1, 32);
    c2 += __shfl_xor(c2, 32); c3 += __shfl_xor(c3, 32);
    if (lane < 16) {
      const float inv = 1.0f / (float)S_N;
      float4 o; o.x = c0 * inv; o.y = c1 * inv; o.z = c2 * inv; o.w = c3 * inv;
      *(float4*)&xm[lr][lane * 4] = o;
    }
  };

  auto proj = [&](int g) {
    const int prow = t >> 5;
    const int dgr = t & 31;
    float pv[8];
#pragma unroll
    for (int dd = 0; dd < 8; ++dd) {
      const int d = dgr * 8 + dd;
      float p = bias[d];
#pragma unroll
      for (int k4 = 0; k4 < 16; ++k4) {
        const float4 wv = *(const float4*)&W[(size_t)d * F_N + k4 * 4];
        const float4 xv = *(const float4*)&xm[prow][k4 * 4];
        p = fmaf(wv.x, xv.x, p); p = fmaf(wv.y, xv.y, p);
        p = fmaf(wv.z, xv.z, p); p = fmaf(wv.w, xv.w, p);
      }
      pv[dd] = p;
    }
    const int d0 = dgr * 8;
    const int k0 = d0 >> 5, kgp = (d0 >> 3) & 3;
    v8s h8, l8;
    splitHL8(pv, h8, l8);
    const int idx = (k0 * 64 + kgp * 16 + prow) * 8;
    *(v8s*)&xeHs[g][idx] = h8;
    *(v8s*)&xeLs[g][idx] = l8;
  };

  auto emitg = [&](int g) {
    const int prow = t >> 5;
    const int seg = t & 31;
    const int d8 = seg * 8;
    const int gr = bm0 + g * GR + prow;
    const int ix = sbi[prow];
    __align__(16) float sel[8];
    *(float4*)&sel[0] = *(const float4*)&reg[(size_t)ix * D_N + d8];
    *(float4*)&sel[4] = *(const float4*)&reg[(size_t)ix * D_N + d8 + 4];
#pragma unroll
    for (int tt = 0; tt < T_N; ++tt) {
      float* op = &out[((size_t)gr * T_N + tt) * D_N + d8];
      *(float4*)&op[0] = *(float4*)&sel[0];
      *(float4*)&op[4] = *(float4*)&sel[4];
    }
    const int k0 = d8 >> 5, kgp = (d8 >> 3) & 3;
    const int idx = (k0 * 64 + kgp * 16 + prow) * 8;
    const v8s vh = *(const v8s*)&xeHs[g][idx];
    const v8s vl = *(const v8s*)&xeLs[g][idx];
    float p = 0.f;
#pragma unroll
    for (int j = 0; j < 8; ++j) {
      const float xej = bf2f((ushortT)vh[j]) + bf2f((ushortT)vl[j]);
      const float dd = xej - sel[j];
      p = fmaf(dd, dd, p);
    }
#pragma unroll
    for (int m = 16; m >= 1; m >>= 1) p += __shfl_xor(p, m);
    if (seg == 0) srowloss[g][prow] = p;
  };

  auto block_argmin = [&](int nstrips) {
    if (t < GR) {
      float bv = swv[0][t];
      int bi = swi[0][t];
      for (int s = 1; s < nstrips; ++s) {
        const float ov = swv[s][t];
        const int oi = swi[s][t];
        if (ov < bv || (ov == bv && oi < bi)) { bv = ov; bi = oi; }
      }
      sbi[t] = bi;
    }
  };

  // ---------------- Prologue: stream group 0 (rows 2w,2w+1), 32-deep batches ----
  {
    const v4f* xr0 = (const v4f*)(x + (size_t)(bm0 + 2 * w + 0) * SF_N);
    const v4f* xr1 = (const v4f*)(x + (size_t)(bm0 + 2 * w + 1) * SF_N);
#pragma unroll
    for (int rr = 0; rr < 2; ++rr) {
      const v4f* xw = rr ? xr1 : xr0;
      float c0 = 0.f, c1 = 0.f, c2 = 0.f, c3 = 0.f;
#pragma unroll 1
      for (int i0 = 0; i0 < 128; i0 += 32) {
        v4f sb[32];
#pragma unroll
        for (int u = 0; u < 32; ++u)
          sb[u] = __builtin_nontemporal_load(&xw[(size_t)(i0 + u) * 64 + lane]);
#pragma unroll
        for (int u = 0; u < 32; ++u) {
          c0 += sb[u][0]; c1 += sb[u][1]; c2 += sb[u][2]; c3 += sb[u][3];
        }
      }
      finish_row(c0, c1, c2, c3, 2 * w + rr);
    }
  }
  __syncthreads();
  proj(0);
  __syncthreads();

  // ---------------- Main: score g0 (staggered B order) || stream g1 ------------
  float bvj[4];
  int bij[4];
#pragma unroll
  for (int j = 0; j < 4; ++j) { bvj[j] = 3.4e38f; bij[j] = 0; }
  float r0c[4] = {0.f, 0.f, 0.f, 0.f};
  float r1c[4] = {0.f, 0.f, 0.f, 0.f};
  {
    const v4f* xr0 = (const v4f*)(x + (size_t)(bm0 + GR + 2 * w + 0) * SF_N);
    const v4f* xr1 = (const v4f*)(x + (size_t)(bm0 + GR + 2 * w + 1) * SF_N);
#pragma unroll 1
    for (int ci = 0; ci < 8; ++ci) {
      const int c = (ci + cstag) & 7;         // staggered score window
      const int g0 = w * 32 + c * 4;
      const ushortT* BH = regHs + (size_t)g0 * 4096 + lane * 8;
      const ushortT* BL = regLs + (size_t)g0 * 4096 + lane * 8;
      v4f acc[4];
#pragma unroll
      for (int ni = 0; ni < 4; ++ni) acc[ni] = (v4f){0.f, 0.f, 0.f, 0.f};

      // micro-phase 1: stream 16 chunks of row0 (sequential ci), consume
      {
        v4f sb[16];
#pragma unroll
        for (int u = 0; u < 16; ++u)
          sb[u] = __builtin_nontemporal_load(&xr0[(size_t)(ci * 16 + u) * 64 + lane]);
#pragma unroll
        for (int u = 0; u < 16; ++u) {
          r0c[0] += sb[u][0]; r0c[1] += sb[u][1];
          r0c[2] += sb[u][2]; r0c[3] += sb[u][3];
        }
      }
      // micro-phase 2: score half (k0 = 0..3)
#pragma unroll
      for (int k0 = 0; k0 < 4; ++k0) {
        const int ao = (k0 * 64 + lane) * 8;
        const v8s ah = *(const v8s*)&xeHs[0][ao];
        const v8s al = *(const v8s*)&xeLs[0][ao];
#pragma unroll
        for (int ni = 0; ni < 4; ++ni) {
          const v8s bh = *(const v8s*)&BH[(size_t)(ni * 8 + k0) * 512];
          const v8s bl = *(const v8s*)&BL[(size_t)(ni * 8 + k0) * 512];
          acc[ni] = __builtin_amdgcn_mfma_f32_16x16x32_bf16(ah, bh, acc[ni], 0, 0, 0);
          acc[ni] = __builtin_amdgcn_mfma_f32_16x16x32_bf16(ah, bl, acc[ni], 0, 0, 0);
          acc[ni] = __builtin_amdgcn_mfma_f32_16x16x32_bf16(al, bh, acc[ni], 0, 0, 0);
        }
      }
      // micro-phase 3: stream 16 chunks of row1, consume
      {
        v4f sb[16];
#pragma unroll
        for (int u = 0; u < 16; ++u)
          sb[u] = __builtin_nontemporal_load(&xr1[(size_t)(ci * 16 + u) * 64 + lane]);
#pragma unroll
        for (int u = 0; u < 16; ++u) {
          r1c[0] += sb[u][0]; r1c[1] += sb[u][1];
          r1c[2] += sb[u][2]; r1c[3] += sb[u][3];
        }
      }
      // micro-phase 4: score half (k0 = 4..7)
#pragma unroll
      for (int k0 = 4; k0 < 8; ++k0) {
        const int ao = (k0 * 64 + lane) * 8;
        const v8s ah = *(const v8s*)&xeHs[0][ao];
        const v8s al = *(const v8s*)&xeLs[0][ao];
#pragma unroll
        for (int ni = 0; ni < 4; ++ni) {
          const v8s bh = *(const v8s*)&BH[(size_t)(ni * 8 + k0) * 512];
          const v8s bl = *(const v8s*)&BL[(size_t)(ni * 8 + k0) * 512];
          acc[ni] = __builtin_amdgcn_mfma_f32_16x16x32_bf16(ah, bh, acc[ni], 0, 0, 0);
          acc[ni] = __builtin_amdgcn_mfma_f32_16x16x32_bf16(ah, bl, acc[ni], 0, 0, 0);
          acc[ni] = __builtin_amdgcn_mfma_f32_16x16x32_bf16(al, bh, acc[ni], 0, 0, 0);
        }
      }
      // epilogue: running argmin with INDEX TIE-BREAK (order-independent)
#pragma unroll
      for (int ni = 0; ni < 4; ++ni) {
        const float rq = rsqh[(g0 + ni) * 16 + n16];
        const int col = (g0 + ni) * 16 + n16;
#pragma unroll
        for (int j = 0; j < 4; ++j) {
          const float s = rq - acc[ni][j];
          if (s < bvj[j] || (s == bvj[j] && col < bij[j])) { bvj[j] = s; bij[j] = col; }
        }
      }
    }
  }
#pragma unroll
  for (int j = 0; j < 4; ++j) {
    float v = bvj[j];
    int ix = bij[j];
#pragma unroll
    for (int m = 8; m >= 1; m >>= 1) {
      const float ov = __shfl_xor(v, m);
      const int oi = __shfl_xor(ix, m);
      if (ov < v || (ov == v && oi < ix)) { v = ov; ix = oi; }
    }
    if (n16 == 0) { swv[w][kg * 4 + j] = v; swi[w][kg * 4 + j] = ix; }
  }
  finish_row(r0c[0], r0c[1], r0c[2], r0c[3], 2 * w + 0);
  finish_row(r1c[0], r1c[1], r1c[2], r1c[3], 2 * w + 1);
  __syncthreads();

  block_argmin(8);
  proj(1);
  __syncthreads();
  emitg(0);

  // ---------------- Tail: score g1 (staggered B order) ----------------
#pragma unroll
  for (int j = 0; j < 4; ++j) { bvj[j] = 3.4e38f; bij[j] = 0; }
#pragma unroll 1
  for (int ci = 0; ci < 8; ++ci) {
    const int c = (ci + cstag) & 7;
    const int g0 = w * 32 + c * 4;
    const ushortT* BH = regHs + (size_t)g0 * 4096 + lane * 8;
    const ushortT* BL = regLs + (size_t)g0 * 4096 + lane * 8;
    v4f acc[4];
#pragma unroll
    for (int ni = 0; ni < 4; ++ni) acc[ni] = (v4f){0.f, 0.f, 0.f, 0.f};
#pragma unroll
    for (int k0 = 0; k0 < 8; ++k0) {
      const int ao = (k0 * 64 + lane) * 8;
      const v8s ah = *(const v8s*)&xeHs[1][ao];
      const v8s al = *(const v8s*)&xeLs[1][ao];
#pragma unroll
      for (int ni = 0; ni < 4; ++ni) {
        const v8s bh = *(const v8s*)&BH[(size_t)(ni * 8 + k0) * 512];
        const v8s bl = *(const v8s*)&BL[(size_t)(ni * 8 + k0) * 512];
        acc[ni] = __builtin_amdgcn_mfma_f32_16x16x32_bf16(ah, bh, acc[ni], 0, 0, 0);
        acc[ni] = __builtin_amdgcn_mfma_f32_16x16x32_bf16(ah, bl, acc[ni], 0, 0, 0);
        acc[ni] = __builtin_amdgcn_mfma_f32_16x16x32_bf16(al, bh, acc[ni], 0, 0, 0);
      }
    }
#pragma unroll
    for (int ni = 0; ni < 4; ++ni) {
      const float rq = rsqh[(g0 + ni) * 16 + n16];
      const int col = (g0 + ni) * 16 + n16;
#pragma unroll
      for (int j = 0; j < 4; ++j) {
        const float s = rq - acc[ni][j];
        if (s < bvj[j] || (s == bvj[j] && col < bij[j])) { bvj[j] = s; bij[j] = col; }
      }
    }
  }
#pragma unroll
  for (int j = 0; j < 4; ++j) {
    float v = bvj[j];
    int ix = bij[j];
#pragma unroll
    for (int m = 8; m >= 1; m >>= 1) {
      const float ov = __shfl_xor(v, m);
      const int oi = __shfl_xor(ix, m);
      if (ov < v || (ov == v && oi < ix)) { v = ov; ix = oi; }
    }
    if (n16 == 0) { swv[w][kg * 4 + j] = v; swi[w][kg * 4 + j] = ix; }
  }
  __syncthreads();
  block_argmin(8);
  __syncthreads();
  emitg(1);
  __syncthreads();

  if (t == 0) {
    float lp = 0.f;
#pragma unroll
    for (int r = 0; r < GR; ++r) lp += srowloss[0][r] + srowloss[1][r];
    lossPart[blockIdx.x] = lp;
  }
}

// ---- K2: loss = sum(parts)/B ----
__global__ __launch_bounds__(256) void k_loss(const float* __restrict__ lossPart,
                                              float* __restrict__ out) {
  __shared__ float ws4[4];
  const int t = threadIdx.x;
  float s = lossPart[t];  // exactly 256 parts
#pragma unroll
  for (int m = 32; m >= 1; m >>= 1) s += __shfl_xor(s, m);
  if ((t & 63) == 0) ws4[t >> 6] = s;
  __syncthreads();
  if (t == 0)
    out[(size_t)B_N * T_N * D_N] = (ws4[0] + ws4[1] + ws4[2] + ws4[3]) / (float)B_N;
}

extern "C" void kernel_launch(void* const* d_in, const int* in_sizes, int n_in,
                              void* d_out, int out_size, void* d_ws, size_t ws_size,
                              hipStream_t stream) {
  const float* x    = (const float*)d_in[0];
  const float* W    = (const float*)d_in[1];
  const float* bias = (const float*)d_in[2];
  const float* reg  = (const float*)d_in[3];
  float* out = (float*)d_out;

  // workspace: all regions fully rewritten every call (~4 MB)
  ushortT* regHs = (ushortT*)d_ws;                      // 2 MB, frag-swizzled
  ushortT* regLs = regHs + (size_t)R_N * D_N;           // 2 MB
  float*   rsqh  = (float*)(regLs + (size_t)R_N * D_N); // 4096
  float*   lossPart = rsqh + R_N;                       // 256

  k_prep<<<dim3(R_N / 16), dim3(256), 0, stream>>>(reg, regHs, regLs, rsqh);
  k_fused<<<dim3(NBLK), dim3(512), 0, stream>>>(x, W, bias, reg, regHs, regLs, rsqh,
                                                out, lossPart);
  k_loss<<<dim3(1), dim3(256), 0, stream>>>(lossPart, out);
}

// Round 16
// 326.946 us; speedup vs baseline: 2.5475x; 1.0872x over previous
//
#include <hip/hip_runtime.h>
#include <hip/hip_bf16.h>

typedef unsigned short ushortT;
typedef __attribute__((ext_vector_type(8))) short v8s;
typedef __attribute__((ext_vector_type(4))) float v4f;

// Problem sizes (fixed by reference)
#define B_N   8192
#define S_N   512
#define F_N   64
#define R_N   4096
#define D_N   256
#define T_N   16
#define SF_N  (S_N * F_N)

#define GR    16            // rows per group
#define NBLK  256           // 1 block/CU; 2 groups (32 rows) per block

__device__ __forceinline__ ushortT f2bf(float x) {
  __hip_bfloat16 b = __float2bfloat16(x);
  return *(ushortT*)&b;
}
__device__ __forceinline__ float bf2f(ushortT u) {
  __hip_bfloat16 b = *(__hip_bfloat16*)&u;
  return __bfloat162float(b);
}
__device__ __forceinline__ void splitHL8(const float* v, v8s& h8, v8s& l8) {
  union { short s[8]; v8s v; } H, L;
#pragma unroll
  for (int j = 0; j < 8; ++j) {
    const float x = v[j];
    const ushortT hb = f2bf(x);
    H.s[j] = (short)hb;
    L.s[j] = (short)f2bf(x - bf2f(hb));
  }
  h8 = H.v; l8 = L.v;
}

// ---- K0: reg -> frag-swizzled bf16 H/L + rsqh (verified R8-R15) --------------
__global__ __launch_bounds__(256) void k_prep(const float* __restrict__ reg,
                                              ushortT* __restrict__ regHs,
                                              ushortT* __restrict__ regLs,
                                              float* __restrict__ rsqh) {
  const int g = blockIdx.x;
  const int t = threadIdx.x;
  const int lane = t & 63;
  const int q = t >> 6;
  const int n16 = lane & 15;
  const int kg = lane >> 4;
  const int row = g * 16 + n16;
#pragma unroll
  for (int h = 0; h < 2; ++h) {
    const int k0 = q + h * 4;
    float v[8];
    *(float4*)&v[0] = *(const float4*)&reg[(size_t)row * D_N + k0 * 32 + kg * 8];
    *(float4*)&v[4] = *(const float4*)&reg[(size_t)row * D_N + k0 * 32 + kg * 8 + 4];
    v8s h8, l8;
    splitHL8(v, h8, l8);
    const size_t o = ((size_t)(g * 8 + k0) * 64 + lane) * 8;
    *(v8s*)&regHs[o] = h8;
    *(v8s*)&regLs[o] = l8;
  }
  const int r16 = t >> 4, seg = t & 15;
  const float* rp = &reg[(size_t)(g * 16 + r16) * D_N + seg * 16];
  float s = 0.f;
#pragma unroll
  for (int j = 0; j < 4; ++j) {
    const float4 v = *(const float4*)&rp[j * 4];
    s += v.x * v.x + v.y * v.y + v.z * v.z + v.w * v.w;
  }
#pragma unroll
  for (int m = 8; m >= 1; m >>= 1) s += __shfl_xor(s, m);
  if (seg == 0) rsqh[g * 16 + r16] = 0.5f * s;
}

// ---- Fused: {stream g1 || score g0 half} then shared-B tail for both groups --
__global__ __launch_bounds__(512, 2) void k_fused(const float* __restrict__ x,
                                                  const float* __restrict__ W,
                                                  const float* __restrict__ bias,
                                                  const float* __restrict__ reg,
                                                  const ushortT* __restrict__ regHs,
                                                  const ushortT* __restrict__ regLs,
                                                  const float* __restrict__ rsqh,
                                                  float* __restrict__ out,
                                                  float* __restrict__ lossPart) {
  __shared__ __align__(16) float xm[GR][68];
  __shared__ __align__(16) ushortT xeHs[2][4096];
  __shared__ __align__(16) ushortT xeLs[2][4096];
  __shared__ float swv[8][GR];
  __shared__ int   swi[8][GR];
  __shared__ float srowloss[2][GR];
  __shared__ int   sbi[GR];

  const int t = threadIdx.x;
  const int w = t >> 6;
  const int lane = t & 63;
  const int bm0 = blockIdx.x * (2 * GR);
  const int n16 = lane & 15;
  const int kg = lane >> 4;

  auto finish_row = [&](float c0, float c1, float c2, float c3, int lr) {
    c0 += __shfl_xor(c0, 16); c1 += __shfl_xor(c1, 16);
    c2 += __shfl_xor(c2, 16); c3 += __shfl_xor(c3, 16);
    c0 += __shfl_xor(c0, 32); c1 += __shfl_xor(c1, 32);
    c2 += __shfl_xor(c2, 32); c3 += __shfl_xor(c3, 32);
    if (lane < 16) {
      const float inv = 1.0f / (float)S_N;
      float4 o; o.x = c0 * inv; o.y = c1 * inv; o.z = c2 * inv; o.w = c3 * inv;
      *(float4*)&xm[lr][lane * 4] = o;
    }
  };

  auto proj = [&](int g) {
    const int prow = t >> 5;
    const int dgr = t & 31;
    float pv[8];
#pragma unroll
    for (int dd = 0; dd < 8; ++dd) {
      const int d = dgr * 8 + dd;
      float p = bias[d];
#pragma unroll
      for (int k4 = 0; k4 < 16; ++k4) {
        const float4 wv = *(const float4*)&W[(size_t)d * F_N + k4 * 4];
        const float4 xv = *(const float4*)&xm[prow][k4 * 4];
        p = fmaf(wv.x, xv.x, p); p = fmaf(wv.y, xv.y, p);
        p = fmaf(wv.z, xv.z, p); p = fmaf(wv.w, xv.w, p);
      }
      pv[dd] = p;
    }
    const int d0 = dgr * 8;
    const int k0 = d0 >> 5, kgp = (d0 >> 3) & 3;
    v8s h8, l8;
    splitHL8(pv, h8, l8);
    const int idx = (k0 * 64 + kgp * 16 + prow) * 8;
    *(v8s*)&xeHs[g][idx] = h8;
    *(v8s*)&xeLs[g][idx] = l8;
  };

  auto emitg = [&](int g) {
    const int prow = t >> 5;
    const int seg = t & 31;
    const int d8 = seg * 8;
    const int gr = bm0 + g * GR + prow;
    const int ix = sbi[prow];
    __align__(16) float sel[8];
    *(float4*)&sel[0] = *(const float4*)&reg[(size_t)ix * D_N + d8];
    *(float4*)&sel[4] = *(const float4*)&reg[(size_t)ix * D_N + d8 + 4];
#pragma unroll
    for (int tt = 0; tt < T_N; ++tt) {
      float* op = &out[((size_t)gr * T_N + tt) * D_N + d8];
      *(float4*)&op[0] = *(float4*)&sel[0];
      *(float4*)&op[4] = *(float4*)&sel[4];
    }
    const int k0 = d8 >> 5, kgp = (d8 >> 3) & 3;
    const int idx = (k0 * 64 + kgp * 16 + prow) * 8;
    const v8s vh = *(const v8s*)&xeHs[g][idx];
    const v8s vl = *(const v8s*)&xeLs[g][idx];
    float p = 0.f;
#pragma unroll
    for (int j = 0; j < 8; ++j) {
      const float xej = bf2f((ushortT)vh[j]) + bf2f((ushortT)vl[j]);
      const float dd = xej - sel[j];
      p = fmaf(dd, dd, p);
    }
#pragma unroll
    for (int m = 16; m >= 1; m >>= 1) p += __shfl_xor(p, m);
    if (seg == 0) srowloss[g][prow] = p;
  };

  auto block_argmin = [&]() {
    if (t < GR) {
      float bv = swv[0][t];
      int bi = swi[0][t];
#pragma unroll
      for (int s = 1; s < 8; ++s) {
        const float ov = swv[s][t];
        const int oi = swi[s][t];
        if (ov < bv || (ov == bv && oi < bi)) { bv = ov; bi = oi; }
      }
      sbi[t] = bi;
    }
  };

  // strip-reduce one group's running argmin (regs) into swv/swi
  auto write_strips = [&](float* bvj, int* bij) {
#pragma unroll
    for (int j = 0; j < 4; ++j) {
      float v = bvj[j];
      int ix = bij[j];
#pragma unroll
      for (int m = 8; m >= 1; m >>= 1) {
        const float ov = __shfl_xor(v, m);
        const int oi = __shfl_xor(ix, m);
        if (ov < v || (ov == v && oi < ix)) { v = ov; ix = oi; }
      }
      if (n16 == 0) { swv[w][kg * 4 + j] = v; swi[w][kg * 4 + j] = ix; }
    }
  };

  // ---------------- Prologue: stream group 0 (rows 2w,2w+1), 32-deep ----------
  {
    const v4f* xr0 = (const v4f*)(x + (size_t)(bm0 + 2 * w + 0) * SF_N);
    const v4f* xr1 = (const v4f*)(x + (size_t)(bm0 + 2 * w + 1) * SF_N);
#pragma unroll
    for (int rr = 0; rr < 2; ++rr) {
      const v4f* xw = rr ? xr1 : xr0;
      float c0 = 0.f, c1 = 0.f, c2 = 0.f, c3 = 0.f;
#pragma unroll 1
      for (int i0 = 0; i0 < 128; i0 += 32) {
        v4f sb[32];
#pragma unroll
        for (int u = 0; u < 32; ++u)
          sb[u] = __builtin_nontemporal_load(&xw[(size_t)(i0 + u) * 64 + lane]);
#pragma unroll
        for (int u = 0; u < 32; ++u) {
          c0 += sb[u][0]; c1 += sb[u][1]; c2 += sb[u][2]; c3 += sb[u][3];
        }
      }
      finish_row(c0, c1, c2, c3, 2 * w + rr);
    }
  }
  __syncthreads();
  proj(0);
  __syncthreads();

  // ---------------- Main: stream g1 || score g0 on c = 0..3 (fine grain) ------
  float bvj0[4], bvj1[4];
  int bij0[4], bij1[4];
#pragma unroll
  for (int j = 0; j < 4; ++j) {
    bvj0[j] = 3.4e38f; bij0[j] = 0;
    bvj1[j] = 3.4e38f; bij1[j] = 0;
  }
  float r0c[4] = {0.f, 0.f, 0.f, 0.f};
  float r1c[4] = {0.f, 0.f, 0.f, 0.f};
  {
    const v4f* xr0 = (const v4f*)(x + (size_t)(bm0 + GR + 2 * w + 0) * SF_N);
    const v4f* xr1 = (const v4f*)(x + (size_t)(bm0 + GR + 2 * w + 1) * SF_N);
    v4f acc[4];
#pragma unroll 1
    for (int ci = 0; ci < 8; ++ci) {
      const int c = ci >> 1;                 // c = 0..3, two ci steps each
      const int g0c = w * 32 + c * 4;
      const ushortT* BH = regHs + (size_t)g0c * 4096 + lane * 8;
      const ushortT* BL = regLs + (size_t)g0c * 4096 + lane * 8;
      const int kbase = (ci & 1) * 4;
      if ((ci & 1) == 0) {
#pragma unroll
        for (int ni = 0; ni < 4; ++ni) acc[ni] = (v4f){0.f, 0.f, 0.f, 0.f};
      }
      // stream 16 chunks of row0, consume
      {
        v4f sb[16];
#pragma unroll
        for (int u = 0; u < 16; ++u)
          sb[u] = __builtin_nontemporal_load(&xr0[(size_t)(ci * 16 + u) * 64 + lane]);
#pragma unroll
        for (int u = 0; u < 16; ++u) {
          r0c[0] += sb[u][0]; r0c[1] += sb[u][1];
          r0c[2] += sb[u][2]; r0c[3] += sb[u][3];
        }
      }
      // score quarter: k0 = kbase+0, kbase+1
#pragma unroll
      for (int kk = 0; kk < 2; ++kk) {
        const int k0 = kbase + kk;
        const int ao = (k0 * 64 + lane) * 8;
        const v8s ah = *(const v8s*)&xeHs[0][ao];
        const v8s al = *(const v8s*)&xeLs[0][ao];
#pragma unroll
        for (int ni = 0; ni < 4; ++ni) {
          const v8s bh = *(const v8s*)&BH[(size_t)(ni * 8 + k0) * 512];
          const v8s bl = *(const v8s*)&BL[(size_t)(ni * 8 + k0) * 512];
          acc[ni] = __builtin_amdgcn_mfma_f32_16x16x32_bf16(ah, bh, acc[ni], 0, 0, 0);
          acc[ni] = __builtin_amdgcn_mfma_f32_16x16x32_bf16(ah, bl, acc[ni], 0, 0, 0);
          acc[ni] = __builtin_amdgcn_mfma_f32_16x16x32_bf16(al, bh, acc[ni], 0, 0, 0);
        }
      }
      // stream 16 chunks of row1, consume
      {
        v4f sb[16];
#pragma unroll
        for (int u = 0; u < 16; ++u)
          sb[u] = __builtin_nontemporal_load(&xr1[(size_t)(ci * 16 + u) * 64 + lane]);
#pragma unroll
        for (int u = 0; u < 16; ++u) {
          r1c[0] += sb[u][0]; r1c[1] += sb[u][1];
          r1c[2] += sb[u][2]; r1c[3] += sb[u][3];
        }
      }
      // score quarter: k0 = kbase+2, kbase+3
#pragma unroll
      for (int kk = 2; kk < 4; ++kk) {
        const int k0 = kbase + kk;
        const int ao = (k0 * 64 + lane) * 8;
        const v8s ah = *(const v8s*)&xeHs[0][ao];
        const v8s al = *(const v8s*)&xeLs[0][ao];
#pragma unroll
        for (int ni = 0; ni < 4; ++ni) {
          const v8s bh = *(const v8s*)&BH[(size_t)(ni * 8 + k0) * 512];
          const v8s bl = *(const v8s*)&BL[(size_t)(ni * 8 + k0) * 512];
          acc[ni] = __builtin_amdgcn_mfma_f32_16x16x32_bf16(ah, bh, acc[ni], 0, 0, 0);
          acc[ni] = __builtin_amdgcn_mfma_f32_16x16x32_bf16(ah, bl, acc[ni], 0, 0, 0);
          acc[ni] = __builtin_amdgcn_mfma_f32_16x16x32_bf16(al, bh, acc[ni], 0, 0, 0);
        }
      }
      if (ci & 1) {  // epilogue for c (both k-halves done)
#pragma unroll
        for (int ni = 0; ni < 4; ++ni) {
          const float rq = rsqh[(g0c + ni) * 16 + n16];
          const int col = (g0c + ni) * 16 + n16;
#pragma unroll
          for (int j = 0; j < 4; ++j) {
            const float s = rq - acc[ni][j];
            if (s < bvj0[j] || (s == bvj0[j] && col < bij0[j])) { bvj0[j] = s; bij0[j] = col; }
          }
        }
      }
    }
  }
  finish_row(r0c[0], r0c[1], r0c[2], r0c[3], 2 * w + 0);
  finish_row(r1c[0], r1c[1], r1c[2], r1c[3], 2 * w + 1);
  __syncthreads();
  proj(1);
  __syncthreads();

  // ---------------- Tail A: c = 4..7, BOTH groups share each B load -----------
#pragma unroll 1
  for (int c = 4; c < 8; ++c) {
    const int g0c = w * 32 + c * 4;
    const ushortT* BH = regHs + (size_t)g0c * 4096 + lane * 8;
    const ushortT* BL = regLs + (size_t)g0c * 4096 + lane * 8;
    v4f a0[4], a1[4];
#pragma unroll
    for (int ni = 0; ni < 4; ++ni) {
      a0[ni] = (v4f){0.f, 0.f, 0.f, 0.f};
      a1[ni] = (v4f){0.f, 0.f, 0.f, 0.f};
    }
#pragma unroll
    for (int k0 = 0; k0 < 8; ++k0) {
      const int ao = (k0 * 64 + lane) * 8;
      const v8s ah0 = *(const v8s*)&xeHs[0][ao];
      const v8s al0 = *(const v8s*)&xeLs[0][ao];
      const v8s ah1 = *(const v8s*)&xeHs[1][ao];
      const v8s al1 = *(const v8s*)&xeLs[1][ao];
#pragma unroll
      for (int ni = 0; ni < 4; ++ni) {
        const v8s bh = *(const v8s*)&BH[(size_t)(ni * 8 + k0) * 512];
        const v8s bl = *(const v8s*)&BL[(size_t)(ni * 8 + k0) * 512];
        a0[ni] = __builtin_amdgcn_mfma_f32_16x16x32_bf16(ah0, bh, a0[ni], 0, 0, 0);
        a0[ni] = __builtin_amdgcn_mfma_f32_16x16x32_bf16(ah0, bl, a0[ni], 0, 0, 0);
        a0[ni] = __builtin_amdgcn_mfma_f32_16x16x32_bf16(al0, bh, a0[ni], 0, 0, 0);
        a1[ni] = __builtin_amdgcn_mfma_f32_16x16x32_bf16(ah1, bh, a1[ni], 0, 0, 0);
        a1[ni] = __builtin_amdgcn_mfma_f32_16x16x32_bf16(ah1, bl, a1[ni], 0, 0, 0);
        a1[ni] = __builtin_amdgcn_mfma_f32_16x16x32_bf16(al1, bh, a1[ni], 0, 0, 0);
      }
    }
#pragma unroll
    for (int ni = 0; ni < 4; ++ni) {
      const float rq = rsqh[(g0c + ni) * 16 + n16];
      const int col = (g0c + ni) * 16 + n16;
#pragma unroll
      for (int j = 0; j < 4; ++j) {
        const float s0 = rq - a0[ni][j];
        if (s0 < bvj0[j] || (s0 == bvj0[j] && col < bij0[j])) { bvj0[j] = s0; bij0[j] = col; }
        const float s1 = rq - a1[ni][j];
        if (s1 < bvj1[j] || (s1 == bvj1[j] && col < bij1[j])) { bvj1[j] = s1; bij1[j] = col; }
      }
    }
  }

  // g0 complete -> argmin -> emit (writes drain under Tail B)
  write_strips(bvj0, bij0);
  __syncthreads();
  block_argmin();
  __syncthreads();
  emitg(0);

  // ---------------- Tail B: c = 0..3, g1 only ----------------
#pragma unroll 1
  for (int c = 0; c < 4; ++c) {
    const int g0c = w * 32 + c * 4;
    const ushortT* BH = regHs + (size_t)g0c * 4096 + lane * 8;
    const ushortT* BL = regLs + (size_t)g0c * 4096 + lane * 8;
    v4f a1[4];
#pragma unroll
    for (int ni = 0; ni < 4; ++ni) a1[ni] = (v4f){0.f, 0.f, 0.f, 0.f};
#pragma unroll
    for (int k0 = 0; k0 < 8; ++k0) {
      const int ao = (k0 * 64 + lane) * 8;
      const v8s ah1 = *(const v8s*)&xeHs[1][ao];
      const v8s al1 = *(const v8s*)&xeLs[1][ao];
#pragma unroll
      for (int ni = 0; ni < 4; ++ni) {
        const v8s bh = *(const v8s*)&BH[(size_t)(ni * 8 + k0) * 512];
        const v8s bl = *(const v8s*)&BL[(size_t)(ni * 8 + k0) * 512];
        a1[ni] = __builtin_amdgcn_mfma_f32_16x16x32_bf16(ah1, bh, a1[ni], 0, 0, 0);
        a1[ni] = __builtin_amdgcn_mfma_f32_16x16x32_bf16(ah1, bl, a1[ni], 0, 0, 0);
        a1[ni] = __builtin_amdgcn_mfma_f32_16x16x32_bf16(al1, bh, a1[ni], 0, 0, 0);
      }
    }
#pragma unroll
    for (int ni = 0; ni < 4; ++ni) {
      const float rq = rsqh[(g0c + ni) * 16 + n16];
      const int col = (g0c + ni) * 16 + n16;
#pragma unroll
      for (int j = 0; j < 4; ++j) {
        const float s1 = rq - a1[ni][j];
        if (s1 < bvj1[j] || (s1 == bvj1[j] && col < bij1[j])) { bvj1[j] = s1; bij1[j] = col; }
      }
    }
  }
  write_strips(bvj1, bij1);
  __syncthreads();
  block_argmin();
  __syncthreads();
  emitg(1);
  __syncthreads();

  if (t == 0) {
    float lp = 0.f;
#pragma unroll
    for (int r = 0; r < GR; ++r) lp += srowloss[0][r] + srowloss[1][r];
    lossPart[blockIdx.x] = lp;
  }
}

// ---- K2: loss = sum(parts)/B ----
__global__ __launch_bounds__(256) void k_loss(const float* __restrict__ lossPart,
                                              float* __restrict__ out) {
  __shared__ float ws4[4];
  const int t = threadIdx.x;
  float s = lossPart[t];  // exactly 256 parts
#pragma unroll
  for (int m = 32; m >= 1; m >>= 1) s += __shfl_xor(s, m);
  if ((t & 63) == 0) ws4[t >> 6] = s;
  __syncthreads();
  if (t == 0)
    out[(size_t)B_N * T_N * D_N] = (ws4[0] + ws4[1] + ws4[2] + ws4[3]) / (float)B_N;
}

extern "C" void kernel_launch(void* const* d_in, const int* in_sizes, int n_in,
                              void* d_out, int out_size, void* d_ws, size_t ws_size,
                              hipStream_t stream) {
  const float* x    = (const float*)d_in[0];
  const float* W    = (const float*)d_in[1];
  const float* bias = (const float*)d_in[2];
  const float* reg  = (const float*)d_in[3];
  float* out = (float*)d_out;

  // workspace: all regions fully rewritten every call (~4 MB)
  ushortT* regHs = (ushortT*)d_ws;                      // 2 MB, frag-swizzled
  ushortT* regLs = regHs + (size_t)R_N * D_N;           // 2 MB
  float*   rsqh  = (float*)(regLs + (size_t)R_N * D_N); // 4096
  float*   lossPart = rsqh + R_N;                       // 256

  k_prep<<<dim3(R_N / 16), dim3(256), 0, stream>>>(reg, regHs, regLs, rsqh);
  k_fused<<<dim3(NBLK), dim3(512), 0, stream>>>(x, W, bias, reg, regHs, regLs, rsqh,
                                                out, lossPart);
  k_loss<<<dim3(1), dim3(256), 0, stream>>>(lossPart, out);
}